// Round 8
// baseline (267.315 us; speedup 1.0000x reference)
//
#include <hip/hip_runtime.h>
#include <hip/hip_fp16.h>
#include <math.h>

#define B_ 128
#define C_ 10
#define R_ 8192
#define I_ 8
#define O_ 16

typedef __attribute__((ext_vector_type(8))) _Float16 half8;
typedef __attribute__((ext_vector_type(16))) float f32x16;

#define XROW 512           // uints per x r-row: 128 b * 4
#define WROW 64            // uints per W row: 16 o * 4
#define SBO (C_ * B_ * O_) // 20480

__device__ __forceinline__ unsigned pk2(float a, float b) {
    __half2 h = __floats2half2_rn(a, b);
    return *(unsigned*)&h;
}

// ---------------------------------------------------------------------------
// fused_iter<TR,MINW>: one routing iteration, r-tiles of TR rows.
// r7 post-mortem: occupancy was GRID-capped (1024 blocks = 4/CU = 16 waves
// = 50% hard ceiling) -- LDS/VGPR trims couldn't help. TR=4 -> 2048 blocks
// (8/CU assigned), LDS 18.7 KB, per-wave chains halved.
// x restored to LDS with the r4-verified XOR swizzle (dword ^= rr<<2 ==
// (b^rr)*4: contiguous 16B per (r,b), conflict-free stage + read, and
// coalesced global x loads -- fixes r7's scattered per-lane x reads).
// Register ledger: r7 body clean at cap 102 ((256,5)); TR=4 body is smaller
// (xbr[2], dacc[2]). TR=8 fallback instantiated at (256,4) (r3-like, clean).
// Output: part[slot=blockIdx.x][c][b][o] fp16 partial s sums.
// ---------------------------------------------------------------------------
template<int TR, int MINW>
__global__ __launch_bounds__(256, MINW) void fused_iter(const float* __restrict__ x,
                                                        const float* __restrict__ w,
                                                        const float* __restrict__ vsum,  // [C][B][16]
                                                        __half* __restrict__ part,
                                                        int mode) {
    constexpr int RP = TR / 2;          // r-pairs per tile
    constexpr int WR = C_ * TR;         // staged W rows (zero row at index WR)
    constexpr int LOG2TR = (TR == 8) ? 3 : 2;
    __shared__ unsigned xls[TR * XROW];          // TR=4: 8 KB
    __shared__ unsigned wls[(WR + 1) * WROW];    // TR=4: 10.25 KB

    const int tid = threadIdx.x;
    const int wave = tid >> 6;
    const int lane = tid & 63;
    const int n = lane & 31;
    const int g = lane >> 5;            // k-half / o-half selector
    const int rp_m = (lane & 31) >> 4;  // r' of this lane's A row
    const int o_m = lane & 15;          // o of this lane's A row
    const int b = wave * 32 + n;        // global batch 0..127
    const int r0 = blockIdx.x * TR;

    // ---- stage x tile fp16, XOR-swizzled ----
#pragma unroll
    for (int k = 0; k < TR; ++k) {
        const int f = k * 256 + tid;            // 0..TR*256-1
        const int q = f & 1;
        const int rr = (f >> 1) & (TR - 1);
        const int bb = f >> (1 + LOG2TR);
        const float4 v = *(const float4*)(x + ((size_t)bb * R_ + r0 + rr) * 8 + q * 4);
        *(uint2*)(xls + rr * XROW + ((bb * 4 + q * 2) ^ (rr << 2))) =
            make_uint2(pk2(v.x, v.y), pk2(v.z, v.w));
    }
    // ---- stage W for ALL c fp16: wls[c*TR+r][o][4 b32] ----
    constexpr int NW = WR * 16;                 // uint4 writes total
#pragma unroll
    for (int k = 0; k < (NW + 255) / 256; ++k) {
        const int id = k * 256 + tid;
        if ((NW & 255) == 0 || id < NW) {
            const int o = id & 15;
            const int r = (id >> 4) & (TR - 1);
            const int c = id >> (4 + LOG2TR);
            const float* wp = w + ((size_t)(c * R_ + r0 + r) * 8) * 16 + o;
            const float f0 = wp[0],  f1 = wp[16],  f2 = wp[32],  f3 = wp[48];
            const float f4 = wp[64], f5 = wp[80],  f6 = wp[96],  f7 = wp[112];
            *(uint4*)(wls + (c * TR + r) * WROW + o * 4) =
                make_uint4(pk2(f0, f1), pk2(f2, f3), pk2(f4, f5), pk2(f6, f7));
        }
    }
    if (tid < WROW) wls[WR * WROW + tid] = 0u;
    __syncthreads();

    const int act = (g == rp_m);

    // hoisted x fragments (c-invariant); read compensates the swizzle
    half8 xbr[RP];
#pragma unroll
    for (int rp = 0; rp < RP; ++rp) {
        const int row = 2 * rp + g;
        xbr[rp] = *(const half8*)(xls + row * XROW + ((b * 4) ^ (row << 2)));
    }

    if (mode) {
        // ================= mode 1: softmax-weighted =================
        // ---- phase 2: denominators d[r] = sum_c exp(p[c,r]) ----
        float dinv[RP];
        {
            float dacc[RP];
#pragma unroll
            for (int rp = 0; rp < RP; ++rp) dacc[rp] = 0.f;
#pragma unroll 1
            for (int c = 0; c < C_; ++c) {
                const float4* vp = (const float4*)(vsum + ((size_t)c * B_ + b) * O_ + 4 * g);
                const float4 va = vp[0];   // o = 4g..4g+3
                const float4 vb = vp[2];   // o = 8+4g..
#pragma unroll
                for (int rp = 0; rp < RP; ++rp) {
                    const int woff = act ? ((c * TR + 2 * rp + g) * WROW + o_m * 4)
                                         : (WR * WROW);
                    const half8 a = *(const half8*)(wls + woff);
                    f32x16 u;
#pragma unroll
                    for (int j = 0; j < 16; ++j) u[j] = 0.f;
                    u = __builtin_amdgcn_mfma_f32_32x32x16_f16(a, xbr[rp], u, 0, 0, 0);
                    const float p0 = u[0] * va.x + u[1] * va.y + u[2] * va.z + u[3] * va.w
                                   + u[4] * vb.x + u[5] * vb.y + u[6] * vb.z + u[7] * vb.w;
                    const float p1 = u[8] * va.x + u[9] * va.y + u[10] * va.z + u[11] * va.w
                                   + u[12] * vb.x + u[13] * vb.y + u[14] * vb.z + u[15] * vb.w;
                    const float send = g ? p0 : p1;
                    const float recv = __shfl_xor(send, 32);
                    const float pg = (g ? p1 : p0) + recv;
                    dacc[rp] += __expf(pg);
                }
            }
#pragma unroll
            for (int rp = 0; rp < RP; ++rp) dinv[rp] = 1.0f / dacc[rp];
        }

        // ---- phase 3: weighted accumulation (8-wide acc) ----
#pragma unroll 1
        for (int c = 0; c < C_; ++c) {
            const float4* vp = (const float4*)(vsum + ((size_t)c * B_ + b) * O_ + 4 * g);
            const float4 va = vp[0];
            const float4 vb = vp[2];
            float acc[8];
#pragma unroll
            for (int rp = 0; rp < RP; ++rp) {
                const int woff = act ? ((c * TR + 2 * rp + g) * WROW + o_m * 4)
                                     : (WR * WROW);
                const half8 a = *(const half8*)(wls + woff);
                f32x16 u;
#pragma unroll
                for (int j = 0; j < 16; ++j) u[j] = 0.f;
                u = __builtin_amdgcn_mfma_f32_32x32x16_f16(a, xbr[rp], u, 0, 0, 0);
                const float p0 = u[0] * va.x + u[1] * va.y + u[2] * va.z + u[3] * va.w
                               + u[4] * vb.x + u[5] * vb.y + u[6] * vb.z + u[7] * vb.w;
                const float p1 = u[8] * va.x + u[9] * va.y + u[10] * va.z + u[11] * va.w
                               + u[12] * vb.x + u[13] * vb.y + u[14] * vb.z + u[15] * vb.w;
                const float send = g ? p0 : p1;
                const float recv = __shfl_xor(send, 32);
                const float pg = (g ? p1 : p0) + recv;
                const float w_own = __expf(pg) * dinv[rp];     // weight for r = 2rp+g
                const float w_oth = __shfl_xor(w_own, 32);     // partner's (r = 2rp+(1-g))
                const float c0 = g ? w_oth : w_own;            // r' = 0 rows (u[0..7])
                const float c1 = g ? w_own : w_oth;            // r' = 1 rows (u[8..15])
                if (rp == 0) {
#pragma unroll
                    for (int j = 0; j < 8; ++j) acc[j] = c0 * u[j] + c1 * u[j + 8];
                } else {
#pragma unroll
                    for (int j = 0; j < 8; ++j) acc[j] += c0 * u[j] + c1 * u[j + 8];
                }
            }
            __half* pp = part + (((size_t)blockIdx.x * C_ + c) * B_ + b) * O_;
            *(uint2*)(pp + 4 * g)     = make_uint2(pk2(acc[0], acc[1]), pk2(acc[2], acc[3]));
            *(uint2*)(pp + 8 + 4 * g) = make_uint2(pk2(acc[4], acc[5]), pk2(acc[6], acc[7]));
        }
    } else {
        // ================= mode 0: uniform weights 0.1 =================
#pragma unroll 1
        for (int c = 0; c < C_; ++c) {
            f32x16 acc;
#pragma unroll
            for (int j = 0; j < 16; ++j) acc[j] = 0.f;
#pragma unroll
            for (int rp = 0; rp < RP; ++rp) {
                const int woff = act ? ((c * TR + 2 * rp + g) * WROW + o_m * 4)
                                     : (WR * WROW);
                const half8 a = *(const half8*)(wls + woff);
                acc = __builtin_amdgcn_mfma_f32_32x32x16_f16(a, xbr[rp], acc, 0, 0, 0);
            }
            const float f0 = (acc[0] + acc[8])  * 0.1f, f1 = (acc[1] + acc[9])  * 0.1f;
            const float f2 = (acc[2] + acc[10]) * 0.1f, f3 = (acc[3] + acc[11]) * 0.1f;
            const float f4 = (acc[4] + acc[12]) * 0.1f, f5 = (acc[5] + acc[13]) * 0.1f;
            const float f6 = (acc[6] + acc[14]) * 0.1f, f7 = (acc[7] + acc[15]) * 0.1f;
            __half* pp = part + (((size_t)blockIdx.x * C_ + c) * B_ + b) * O_;
            *(uint2*)(pp + 4 * g)     = make_uint2(pk2(f0, f1), pk2(f2, f3));
            *(uint2*)(pp + 8 + 4 * g) = make_uint2(pk2(f4, f5), pk2(f6, f7));
        }
    }
}

// ---------------------------------------------------------------------------
// reduce1: part2[by][..] = sum of 32 slot-partials. grid (10, slots/32).
// Each thread owns 8 consecutive halfs, uint4 loads (16B/lane, coalesced).
// ---------------------------------------------------------------------------
__global__ __launch_bounds__(256) void reduce1(const __half* __restrict__ part,
                                               float* __restrict__ part2) {
    const int t8 = blockIdx.x * 256 + threadIdx.x;      // 0..2559
    const __half* p = part + (size_t)(blockIdx.y * 32) * SBO + (size_t)t8 * 8;
    float s0 = 0.f, s1 = 0.f, s2 = 0.f, s3 = 0.f;
    float s4 = 0.f, s5 = 0.f, s6 = 0.f, s7 = 0.f;
#pragma unroll 8
    for (int s = 0; s < 32; ++s) {
        const uint4 v = *(const uint4*)(p + (size_t)s * SBO);
        const float2 f0 = __half22float2(*(const __half2*)&v.x);
        const float2 f1 = __half22float2(*(const __half2*)&v.y);
        const float2 f2 = __half22float2(*(const __half2*)&v.z);
        const float2 f3 = __half22float2(*(const __half2*)&v.w);
        s0 += f0.x; s1 += f0.y; s2 += f1.x; s3 += f1.y;
        s4 += f2.x; s5 += f2.y; s6 += f3.x; s7 += f3.y;
    }
    float* q = part2 + (size_t)blockIdx.y * SBO + (size_t)t8 * 8;
    *(float4*)q       = make_float4(s0, s1, s2, s3);
    *(float4*)(q + 4) = make_float4(s4, s5, s6, s7);
}

// ---------------------------------------------------------------------------
// finish_pass: sum ngroups fp32 partials + squash. grid 80.
// t = (c*128+b)*16+o; o spans 16 consecutive lanes -> shfl reduce for ||s||^2.
// mode 0: vsum = v; 1: vsum += v; 2: out = v.
// ---------------------------------------------------------------------------
__global__ __launch_bounds__(256) void finish_pass(const float* __restrict__ part2,
                                                   float* __restrict__ vsum,   // [C][B][16]
                                                   float* __restrict__ out,    // [B][C][16]
                                                   int mode, int ngroups) {
    const int t = blockIdx.x * 256 + threadIdx.x;
    float sum = 0.f;
#pragma unroll 8
    for (int s = 0; s < ngroups; ++s)
        sum += part2[(size_t)s * SBO + t];

    float sq = sum * sum;
    sq += __shfl_xor(sq, 1);
    sq += __shfl_xor(sq, 2);
    sq += __shfl_xor(sq, 4);
    sq += __shfl_xor(sq, 8);
    const float scale = sq / ((1.0f + sq) * sqrtf(sq + 1e-8f));
    const float v = scale * sum;

    if (mode == 0) {
        vsum[t] = v;
    } else if (mode == 1) {
        vsum[t] += v;
    } else {
        const int o = t & 15, b = (t >> 4) & 127, c = t >> 11;
        out[((size_t)b * C_ + c) * O_ + o] = v;
    }
}

extern "C" void kernel_launch(void* const* d_in, const int* in_sizes, int n_in,
                              void* d_out, int out_size, void* d_ws, size_t ws_size,
                              hipStream_t stream) {
    const float* x = (const float*)d_in[0];   // [B,R,8]
    const float* w = (const float*)d_in[1];   // [C,R,8,16]
    float* out = (float*)d_out;               // [B,C,16]

    // TR=4 needs part 2048 slots (83.9 MB); fall back to TR=8 if ws too small.
    const size_t need4 = (size_t)(R_ / 4) * SBO * 2   // part fp16
                       + (size_t)64 * SBO * 4         // part2 fp32 (64 groups)
                       + (size_t)SBO * 4;             // vsum
    const bool use4 = (ws_size >= need4);
    const int slots = use4 ? (R_ / 4) : (R_ / 8);
    const int groups = slots / 32;

    __half* part = (__half*)d_ws;
    float* part2 = (float*)(part + (size_t)slots * SBO);
    float* vsum  = part2 + (size_t)groups * SBO;

    const dim3 fgrid(slots);
    const dim3 rgrid(10, groups);
    const dim3 ggrid(80);

    for (int it = 0; it < 3; ++it) {
        const int mode = (it > 0);
        const int fmode = (it == 2) ? 2 : it;   // finish: 0=set, 1=add, 2=out
        if (use4) fused_iter<4, 5><<<fgrid, 256, 0, stream>>>(x, w, vsum, part, mode);
        else      fused_iter<8, 4><<<fgrid, 256, 0, stream>>>(x, w, vsum, part, mode);
        reduce1<<<rgrid, 256, 0, stream>>>(part, part2);
        finish_pass<<<ggrid, 256, 0, stream>>>(part2, vsum, out, fmode, groups);
    }
}

// Round 9
// 216.972 us; speedup vs baseline: 1.2320x; 1.2320x over previous
//
#include <hip/hip_runtime.h>
#include <hip/hip_fp16.h>
#include <math.h>

#define B_ 128
#define C_ 10
#define R_ 8192
#define I_ 8
#define O_ 16

typedef __attribute__((ext_vector_type(8))) _Float16 half8;
typedef __attribute__((ext_vector_type(16))) float f32x16;

#define XROW 512           // uints per x r-row: 128 b * 4
#define WROW 64            // uints per W row: 16 o * 4
#define WZERO 80           // zero-row index (block-diagonal A trick)
#define SBO (C_ * B_ * O_) // 20480
#define SLOTS 512          // part slots (one per block, 16 r-rows each)
#define NRED 8             // slots summed per reduce1 block -> 64 groups

__device__ __forceinline__ unsigned pk2(float a, float b) {
    __half2 h = __floats2half2_rn(a, b);
    return *(unsigned*)&h;
}

// ---------------------------------------------------------------------------
// fused_iter: one routing iteration. grid 512, block 512 (8 waves), TR=16.
// r8 post-mortem: fused has a ~50us floor insensitive to occupancy (30->57%
// null), mode, TR, VALU volume -- so this round attacks the REDUCTION pyramid
// instead: TR=4 made part 84MB and reduce1 ~24us/iter (~115us of 267 total).
// Structure: two 4-wave subgroups (sg=0,1) each run the r7-clean body on one
// 8-row subtile; their fp16 partials are summed IN-BLOCK via a small LDS
// buffer (aliased over the dead x-stage region, pad-10 rows vs bank clash,
// 2-c batches -> 10 flush barriers). part: 84 -> 20.5 MB (512 slots).
// LDS 72.5 KB -> 2 blocks/CU (16 waves, same as r8). Body math bit-identical
// to r7 per subtile; one extra fp16 rounding at the 16-row partial level.
// Spill tripwire: WRITE_SIZE must be ~20480 KB.
// ---------------------------------------------------------------------------
__global__ __launch_bounds__(512, 4) void fused_iter(const float* __restrict__ x,
                                                     const float* __restrict__ w,
                                                     const float* __restrict__ vsum,  // [C][B][16]
                                                     __half* __restrict__ part,
                                                     int mode) {
    __shared__ unsigned xls[2 * 8 * XROW];       // 32 KB; dead after hoist -> red buffer
    __shared__ unsigned wls[2 * 81 * WROW];      // 40.5 KB (two subtiles, each + zero row)

    const int tid  = threadIdx.x;
    const int wave = tid >> 6;
    const int sg   = wave >> 2;          // subtile 0/1
    const int stid = tid & 255;          // id within subgroup
    const int lane = tid & 63;
    const int n    = lane & 31;
    const int g    = lane >> 5;          // k-half / o-half selector
    const int rp_m = (lane & 31) >> 4;   // r' of this lane's A row
    const int o_m  = lane & 15;          // o of this lane's A row
    const int b    = (wave & 3) * 32 + n;
    const int r0   = blockIdx.x * 16 + sg * 8;

    unsigned* const xbase = xls + sg * (8 * XROW);
    unsigned* const wbase = wls + sg * (81 * WROW);
    unsigned* const red_u = xls;         // [cp(2)][s(2)][b(128)][10] uints (fp16 x2)

    // ---- stage x subtile fp16, XOR-swizzled (r4-verified) ----
#pragma unroll
    for (int k = 0; k < 8; ++k) {
        const int f = k * 256 + stid;            // 0..2047
        const int bb = f >> 4;
        const int rr = (f >> 1) & 7;
        const int q = f & 1;
        const float4 v = *(const float4*)(x + ((size_t)bb * R_ + r0 + rr) * 8 + q * 4);
        *(uint2*)(xbase + rr * XROW + ((bb * 4 + q * 2) ^ (rr << 2))) =
            make_uint2(pk2(v.x, v.y), pk2(v.z, v.w));
    }
    // ---- stage W subtile for ALL c fp16: [c*8+r][o][4 b32] ----
#pragma unroll
    for (int k = 0; k < 5; ++k) {
        const int id = k * 256 + stid;           // 0..1279 = (c, r, o)
        const int o = id & 15;
        const int r = (id >> 4) & 7;
        const int c = id >> 7;
        const float* wp = w + ((size_t)(c * R_ + r0 + r) * 8) * 16 + o;
        const float f0 = wp[0],  f1 = wp[16],  f2 = wp[32],  f3 = wp[48];
        const float f4 = wp[64], f5 = wp[80],  f6 = wp[96],  f7 = wp[112];
        *(uint4*)(wbase + (c * 8 + r) * WROW + o * 4) =
            make_uint4(pk2(f0, f1), pk2(f2, f3), pk2(f4, f5), pk2(f6, f7));
    }
    if (stid < WROW) wbase[WZERO * WROW + stid] = 0u;
    __syncthreads();

    const int act = (g == rp_m);

    // hoisted x fragments (c-invariant); read compensates the swizzle
    half8 xbr[4];
#pragma unroll
    for (int rp = 0; rp < 4; ++rp) {
        const int row = 2 * rp + g;
        xbr[rp] = *(const half8*)(xbase + row * XROW + ((b * 4) ^ (row << 2)));
    }
    __syncthreads();    // xls reads done -> red_u aliasing is now safe

// red write (this sg's 8-row fp16 partial) + 2-c-batch flush:
// flush sums sg0+sg1 in fp32, writes 16-row fp16 partial to part (coalesced).
#define RED_WRITE_AND_FLUSH(A0,A1,A2,A3,A4,A5,A6,A7)                           \
    {                                                                          \
        const int cp = c & 1;                                                  \
        unsigned* rw = red_u + ((cp * 2 + sg) * 128 + b) * 10;                 \
        *(uint2*)(rw + 2 * g)     = make_uint2(pk2(A0, A1), pk2(A2, A3));      \
        *(uint2*)(rw + 4 + 2 * g) = make_uint2(pk2(A4, A5), pk2(A6, A7));      \
        if (cp == 1) {                                                         \
            __syncthreads();                                                   \
            const int cp2 = tid >> 8, t2 = tid & 255;                          \
            const int b2 = t2 >> 1, oh = t2 & 1;                               \
            const int cout = c - 1 + cp2;                                      \
            const unsigned* r0p = red_u + ((cp2 * 2 + 0) * 128 + b2) * 10 + oh * 4; \
            const unsigned* r1p = red_u + ((cp2 * 2 + 1) * 128 + b2) * 10 + oh * 4; \
            const uint2 xa = *(const uint2*)r0p;                               \
            const uint2 xb2 = *(const uint2*)(r0p + 2);                        \
            const uint2 ya = *(const uint2*)r1p;                               \
            const uint2 yb = *(const uint2*)(r1p + 2);                         \
            unsigned ua[4] = {xa.x, xa.y, xb2.x, xb2.y};                       \
            unsigned ub[4] = {ya.x, ya.y, yb.x, yb.y};                         \
            unsigned uo[4];                                                    \
            _Pragma("unroll")                                                  \
            for (int j = 0; j < 4; ++j) {                                      \
                const float2 fa = __half22float2(*(const __half2*)&ua[j]);     \
                const float2 fb = __half22float2(*(const __half2*)&ub[j]);     \
                uo[j] = pk2(fa.x + fb.x, fa.y + fb.y);                         \
            }                                                                  \
            *(uint4*)(part + ((size_t)blockIdx.x * C_ + cout) * (B_ * O_)      \
                      + b2 * O_ + oh * 8) = make_uint4(uo[0], uo[1], uo[2], uo[3]); \
            __syncthreads();                                                   \
        }                                                                      \
    }

    if (mode) {
        // ================= mode 1: softmax-weighted =================
        // ---- phase 2: denominators d[r] = sum_c exp(p[c,r]) ----
        float dinv[4];
        {
            float dacc[4] = {0.f, 0.f, 0.f, 0.f};
#pragma unroll 1
            for (int c = 0; c < C_; ++c) {
                const float4* vp = (const float4*)(vsum + ((size_t)c * B_ + b) * O_ + 4 * g);
                const float4 va = vp[0];   // o = 4g..4g+3
                const float4 vb = vp[2];   // o = 8+4g..
#pragma unroll
                for (int rp = 0; rp < 4; ++rp) {
                    const int woff = act ? ((c * 8 + 2 * rp + g) * WROW + o_m * 4)
                                         : (WZERO * WROW);
                    const half8 a = *(const half8*)(wbase + woff);
                    f32x16 u;
#pragma unroll
                    for (int j = 0; j < 16; ++j) u[j] = 0.f;
                    u = __builtin_amdgcn_mfma_f32_32x32x16_f16(a, xbr[rp], u, 0, 0, 0);
                    const float p0 = u[0] * va.x + u[1] * va.y + u[2] * va.z + u[3] * va.w
                                   + u[4] * vb.x + u[5] * vb.y + u[6] * vb.z + u[7] * vb.w;
                    const float p1 = u[8] * va.x + u[9] * va.y + u[10] * va.z + u[11] * va.w
                                   + u[12] * vb.x + u[13] * vb.y + u[14] * vb.z + u[15] * vb.w;
                    const float send = g ? p0 : p1;
                    const float recv = __shfl_xor(send, 32);
                    const float pg = (g ? p1 : p0) + recv;
                    dacc[rp] += __expf(pg);
                }
            }
#pragma unroll
            for (int rp = 0; rp < 4; ++rp) dinv[rp] = 1.0f / dacc[rp];
        }

        // ---- phase 3: weighted accumulation (8-wide acc) ----
#pragma unroll 1
        for (int c = 0; c < C_; ++c) {
            const float4* vp = (const float4*)(vsum + ((size_t)c * B_ + b) * O_ + 4 * g);
            const float4 va = vp[0];
            const float4 vb = vp[2];
            float acc[8];
#pragma unroll
            for (int rp = 0; rp < 4; ++rp) {
                const int woff = act ? ((c * 8 + 2 * rp + g) * WROW + o_m * 4)
                                     : (WZERO * WROW);
                const half8 a = *(const half8*)(wbase + woff);
                f32x16 u;
#pragma unroll
                for (int j = 0; j < 16; ++j) u[j] = 0.f;
                u = __builtin_amdgcn_mfma_f32_32x32x16_f16(a, xbr[rp], u, 0, 0, 0);
                const float p0 = u[0] * va.x + u[1] * va.y + u[2] * va.z + u[3] * va.w
                               + u[4] * vb.x + u[5] * vb.y + u[6] * vb.z + u[7] * vb.w;
                const float p1 = u[8] * va.x + u[9] * va.y + u[10] * va.z + u[11] * va.w
                               + u[12] * vb.x + u[13] * vb.y + u[14] * vb.z + u[15] * vb.w;
                const float send = g ? p0 : p1;
                const float recv = __shfl_xor(send, 32);
                const float pg = (g ? p1 : p0) + recv;
                const float w_own = __expf(pg) * dinv[rp];     // weight for r = 2rp+g
                const float w_oth = __shfl_xor(w_own, 32);     // partner's (r = 2rp+(1-g))
                const float c0 = g ? w_oth : w_own;            // r' = 0 rows (u[0..7])
                const float c1 = g ? w_own : w_oth;            // r' = 1 rows (u[8..15])
                if (rp == 0) {
#pragma unroll
                    for (int j = 0; j < 8; ++j) acc[j] = c0 * u[j] + c1 * u[j + 8];
                } else {
#pragma unroll
                    for (int j = 0; j < 8; ++j) acc[j] += c0 * u[j] + c1 * u[j + 8];
                }
            }
            RED_WRITE_AND_FLUSH(acc[0], acc[1], acc[2], acc[3],
                                acc[4], acc[5], acc[6], acc[7]);
        }
    } else {
        // ================= mode 0: uniform weights 0.1 =================
#pragma unroll 1
        for (int c = 0; c < C_; ++c) {
            f32x16 acc;
#pragma unroll
            for (int j = 0; j < 16; ++j) acc[j] = 0.f;
#pragma unroll
            for (int rp = 0; rp < 4; ++rp) {
                const int woff = act ? ((c * 8 + 2 * rp + g) * WROW + o_m * 4)
                                     : (WZERO * WROW);
                const half8 a = *(const half8*)(wbase + woff);
                acc = __builtin_amdgcn_mfma_f32_32x32x16_f16(a, xbr[rp], acc, 0, 0, 0);
            }
            const float f0 = (acc[0] + acc[8])  * 0.1f, f1 = (acc[1] + acc[9])  * 0.1f;
            const float f2 = (acc[2] + acc[10]) * 0.1f, f3 = (acc[3] + acc[11]) * 0.1f;
            const float f4 = (acc[4] + acc[12]) * 0.1f, f5 = (acc[5] + acc[13]) * 0.1f;
            const float f6 = (acc[6] + acc[14]) * 0.1f, f7 = (acc[7] + acc[15]) * 0.1f;
            RED_WRITE_AND_FLUSH(f0, f1, f2, f3, f4, f5, f6, f7);
        }
    }
#undef RED_WRITE_AND_FLUSH
}

// ---------------------------------------------------------------------------
// reduce1: part2[by][..] = sum of NRED=8 slot-partials. grid (10, 64) = 640
// blocks. Each thread owns 8 consecutive halfs, uint4 loads (coalesced).
// ---------------------------------------------------------------------------
__global__ __launch_bounds__(256) void reduce1(const __half* __restrict__ part,
                                               float* __restrict__ part2) {
    const int t8 = blockIdx.x * 256 + threadIdx.x;      // 0..2559
    const __half* p = part + (size_t)(blockIdx.y * NRED) * SBO + (size_t)t8 * 8;
    float s0 = 0.f, s1 = 0.f, s2 = 0.f, s3 = 0.f;
    float s4 = 0.f, s5 = 0.f, s6 = 0.f, s7 = 0.f;
#pragma unroll
    for (int s = 0; s < NRED; ++s) {
        const uint4 v = *(const uint4*)(p + (size_t)s * SBO);
        const float2 f0 = __half22float2(*(const __half2*)&v.x);
        const float2 f1 = __half22float2(*(const __half2*)&v.y);
        const float2 f2 = __half22float2(*(const __half2*)&v.z);
        const float2 f3 = __half22float2(*(const __half2*)&v.w);
        s0 += f0.x; s1 += f0.y; s2 += f1.x; s3 += f1.y;
        s4 += f2.x; s5 += f2.y; s6 += f3.x; s7 += f3.y;
    }
    float* q = part2 + (size_t)blockIdx.y * SBO + (size_t)t8 * 8;
    *(float4*)q       = make_float4(s0, s1, s2, s3);
    *(float4*)(q + 4) = make_float4(s4, s5, s6, s7);
}

// ---------------------------------------------------------------------------
// finish_pass: sum SLOTS/NRED=64 fp32 partials + squash. grid 80.
// t = (c*128+b)*16+o; o spans 16 consecutive lanes -> shfl reduce for ||s||^2.
// mode 0: vsum = v; 1: vsum += v; 2: out = v.
// ---------------------------------------------------------------------------
__global__ __launch_bounds__(256) void finish_pass(const float* __restrict__ part2,
                                                   float* __restrict__ vsum,   // [C][B][16]
                                                   float* __restrict__ out,    // [B][C][16]
                                                   int mode) {
    const int t = blockIdx.x * 256 + threadIdx.x;
    float sum = 0.f;
#pragma unroll 8
    for (int s = 0; s < SLOTS / NRED; ++s)
        sum += part2[(size_t)s * SBO + t];

    float sq = sum * sum;
    sq += __shfl_xor(sq, 1);
    sq += __shfl_xor(sq, 2);
    sq += __shfl_xor(sq, 4);
    sq += __shfl_xor(sq, 8);
    const float scale = sq / ((1.0f + sq) * sqrtf(sq + 1e-8f));
    const float v = scale * sum;

    if (mode == 0) {
        vsum[t] = v;
    } else if (mode == 1) {
        vsum[t] += v;
    } else {
        const int o = t & 15, b = (t >> 4) & 127, c = t >> 11;
        out[((size_t)b * C_ + c) * O_ + o] = v;
    }
}

extern "C" void kernel_launch(void* const* d_in, const int* in_sizes, int n_in,
                              void* d_out, int out_size, void* d_ws, size_t ws_size,
                              hipStream_t stream) {
    const float* x = (const float*)d_in[0];   // [B,R,8]
    const float* w = (const float*)d_in[1];   // [C,R,8,16]
    float* out = (float*)d_out;               // [B,C,16]

    __half* part = (__half*)d_ws;                          // 512*20480 fp16 = 21.0 MB
    float* part2 = (float*)(part + (size_t)SLOTS * SBO);   // 64*20480 fp32 = 5.2 MB
    float* vsum  = part2 + (size_t)(SLOTS / NRED) * SBO;   // 20480 f ([C][B][16])

    const dim3 fgrid(R_ / 16);             // 512 blocks of 512 threads
    const dim3 rgrid(10, SLOTS / NRED);    // (10,64) = 640 blocks
    const dim3 ggrid(80);

    for (int it = 0; it < 3; ++it) {
        const int mode = (it > 0);
        const int fmode = (it == 2) ? 2 : it;   // finish: 0=set, 1=add, 2=out
        fused_iter<<<fgrid, 512, 0, stream>>>(x, w, vsum, part, mode);
        reduce1<<<rgrid, 256, 0, stream>>>(part, part2);
        finish_pass<<<ggrid, 256, 0, stream>>>(part2, vsum, out, fmode);
    }
}

// Round 10
// 203.672 us; speedup vs baseline: 1.3125x; 1.0653x over previous
//
#include <hip/hip_runtime.h>
#include <hip/hip_fp16.h>
#include <math.h>

#define B_ 128
#define C_ 10
#define R_ 8192
#define I_ 8
#define O_ 16

typedef __attribute__((ext_vector_type(8))) _Float16 half8;
typedef __attribute__((ext_vector_type(16))) float f32x16;

#define XROW 512           // uints per x r-row: 128 b * 4
#define WROW 64            // uints per W row: 16 o * 4
#define WZERO 80           // zero-row index (block-diagonal A trick)
#define SBO (C_ * B_ * O_) // 20480
#define SLOTS 512          // part slots (one per block, 16 r-rows each)

__device__ __forceinline__ unsigned pk2(float a, float b) {
    __half2 h = __floats2half2_rn(a, b);
    return *(unsigned*)&h;
}

// ---------------------------------------------------------------------------
// fused_iter: one routing iteration. grid 512, block 512 (8 waves), TR=16.
// Structure from r9 (WIN: in-block LDS reduction, part = 21 MB, WRITE clean).
// r10 change: zero16 hoisted back as MFMA C-operand (D != C). The r9 config
// is LDS-capped (74 KB -> 2 blocks/CU) with launch_bounds(512,4) -> VGPR cap
// 128, the same budget where r3 carried zero16 cleanly. Saves 16 v_mov x 80
// MFMAs per wave (~10% of VALU issue). Math bit-identical.
// Spill tripwire: WRITE_SIZE must stay 20480 KB exactly.
// ---------------------------------------------------------------------------
__global__ __launch_bounds__(512, 4) void fused_iter(const float* __restrict__ x,
                                                     const float* __restrict__ w,
                                                     const float* __restrict__ vsum,  // [C][B][16]
                                                     __half* __restrict__ part,
                                                     int mode) {
    __shared__ unsigned xls[2 * 8 * XROW];       // 32 KB; dead after hoist -> red buffer
    __shared__ unsigned wls[2 * 81 * WROW];      // 40.5 KB (two subtiles, each + zero row)

    const int tid  = threadIdx.x;
    const int wave = tid >> 6;
    const int sg   = wave >> 2;          // subtile 0/1
    const int stid = tid & 255;          // id within subgroup
    const int lane = tid & 63;
    const int n    = lane & 31;
    const int g    = lane >> 5;          // k-half / o-half selector
    const int rp_m = (lane & 31) >> 4;   // r' of this lane's A row
    const int o_m  = lane & 15;          // o of this lane's A row
    const int b    = (wave & 3) * 32 + n;
    const int r0   = blockIdx.x * 16 + sg * 8;

    unsigned* const xbase = xls + sg * (8 * XROW);
    unsigned* const wbase = wls + sg * (81 * WROW);
    unsigned* const red_u = xls;         // [cp(2)][s(2)][b(128)][10] uints (fp16 x2)

    // ---- stage x subtile fp16, XOR-swizzled (r4-verified) ----
#pragma unroll
    for (int k = 0; k < 8; ++k) {
        const int f = k * 256 + stid;            // 0..2047
        const int bb = f >> 4;
        const int rr = (f >> 1) & 7;
        const int q = f & 1;
        const float4 v = *(const float4*)(x + ((size_t)bb * R_ + r0 + rr) * 8 + q * 4);
        *(uint2*)(xbase + rr * XROW + ((bb * 4 + q * 2) ^ (rr << 2))) =
            make_uint2(pk2(v.x, v.y), pk2(v.z, v.w));
    }
    // ---- stage W subtile for ALL c fp16: [c*8+r][o][4 b32] ----
#pragma unroll
    for (int k = 0; k < 5; ++k) {
        const int id = k * 256 + stid;           // 0..1279 = (c, r, o)
        const int o = id & 15;
        const int r = (id >> 4) & 7;
        const int c = id >> 7;
        const float* wp = w + ((size_t)(c * R_ + r0 + r) * 8) * 16 + o;
        const float f0 = wp[0],  f1 = wp[16],  f2 = wp[32],  f3 = wp[48];
        const float f4 = wp[64], f5 = wp[80],  f6 = wp[96],  f7 = wp[112];
        *(uint4*)(wbase + (c * 8 + r) * WROW + o * 4) =
            make_uint4(pk2(f0, f1), pk2(f2, f3), pk2(f4, f5), pk2(f6, f7));
    }
    if (stid < WROW) wbase[WZERO * WROW + stid] = 0u;
    __syncthreads();

    const int act = (g == rp_m);

    // hoisted x fragments (c-invariant); read compensates the swizzle
    half8 xbr[4];
#pragma unroll
    for (int rp = 0; rp < 4; ++rp) {
        const int row = 2 * rp + g;
        xbr[rp] = *(const half8*)(xbase + row * XROW + ((b * 4) ^ (row << 2)));
    }
    __syncthreads();    // xls reads done -> red_u aliasing is now safe

    // hoisted zero accumulator: MFMA C operand (D != C), no per-use init
    f32x16 zero16;
#pragma unroll
    for (int j = 0; j < 16; ++j) zero16[j] = 0.f;

// red write (this sg's 8-row fp16 partial) + 2-c-batch flush:
// flush sums sg0+sg1 in fp32, writes 16-row fp16 partial to part (coalesced).
#define RED_WRITE_AND_FLUSH(A0,A1,A2,A3,A4,A5,A6,A7)                           \
    {                                                                          \
        const int cp = c & 1;                                                  \
        unsigned* rw = red_u + ((cp * 2 + sg) * 128 + b) * 10;                 \
        *(uint2*)(rw + 2 * g)     = make_uint2(pk2(A0, A1), pk2(A2, A3));      \
        *(uint2*)(rw + 4 + 2 * g) = make_uint2(pk2(A4, A5), pk2(A6, A7));      \
        if (cp == 1) {                                                         \
            __syncthreads();                                                   \
            const int cp2 = tid >> 8, t2 = tid & 255;                          \
            const int b2 = t2 >> 1, oh = t2 & 1;                               \
            const int cout = c - 1 + cp2;                                      \
            const unsigned* r0p = red_u + ((cp2 * 2 + 0) * 128 + b2) * 10 + oh * 4; \
            const unsigned* r1p = red_u + ((cp2 * 2 + 1) * 128 + b2) * 10 + oh * 4; \
            const uint2 xa = *(const uint2*)r0p;                               \
            const uint2 xb2 = *(const uint2*)(r0p + 2);                        \
            const uint2 ya = *(const uint2*)r1p;                               \
            const uint2 yb = *(const uint2*)(r1p + 2);                         \
            unsigned ua[4] = {xa.x, xa.y, xb2.x, xb2.y};                       \
            unsigned ub[4] = {ya.x, ya.y, yb.x, yb.y};                         \
            unsigned uo[4];                                                    \
            _Pragma("unroll")                                                  \
            for (int j = 0; j < 4; ++j) {                                      \
                const float2 fa = __half22float2(*(const __half2*)&ua[j]);     \
                const float2 fb = __half22float2(*(const __half2*)&ub[j]);     \
                uo[j] = pk2(fa.x + fb.x, fa.y + fb.y);                         \
            }                                                                  \
            *(uint4*)(part + ((size_t)blockIdx.x * C_ + cout) * (B_ * O_)      \
                      + b2 * O_ + oh * 8) = make_uint4(uo[0], uo[1], uo[2], uo[3]); \
            __syncthreads();                                                   \
        }                                                                      \
    }

    if (mode) {
        // ================= mode 1: softmax-weighted =================
        // ---- phase 2: denominators d[r] = sum_c exp(p[c,r]) ----
        float dinv[4];
        {
            float dacc[4] = {0.f, 0.f, 0.f, 0.f};
#pragma unroll 1
            for (int c = 0; c < C_; ++c) {
                const float4* vp = (const float4*)(vsum + ((size_t)c * B_ + b) * O_ + 4 * g);
                const float4 va = vp[0];   // o = 4g..4g+3
                const float4 vb = vp[2];   // o = 8+4g..
#pragma unroll
                for (int rp = 0; rp < 4; ++rp) {
                    const int woff = act ? ((c * 8 + 2 * rp + g) * WROW + o_m * 4)
                                         : (WZERO * WROW);
                    const half8 a = *(const half8*)(wbase + woff);
                    const f32x16 u = __builtin_amdgcn_mfma_f32_32x32x16_f16(a, xbr[rp], zero16, 0, 0, 0);
                    const float p0 = u[0] * va.x + u[1] * va.y + u[2] * va.z + u[3] * va.w
                                   + u[4] * vb.x + u[5] * vb.y + u[6] * vb.z + u[7] * vb.w;
                    const float p1 = u[8] * va.x + u[9] * va.y + u[10] * va.z + u[11] * va.w
                                   + u[12] * vb.x + u[13] * vb.y + u[14] * vb.z + u[15] * vb.w;
                    const float send = g ? p0 : p1;
                    const float recv = __shfl_xor(send, 32);
                    const float pg = (g ? p1 : p0) + recv;
                    dacc[rp] += __expf(pg);
                }
            }
#pragma unroll
            for (int rp = 0; rp < 4; ++rp) dinv[rp] = 1.0f / dacc[rp];
        }

        // ---- phase 3: weighted accumulation (8-wide acc) ----
#pragma unroll 1
        for (int c = 0; c < C_; ++c) {
            const float4* vp = (const float4*)(vsum + ((size_t)c * B_ + b) * O_ + 4 * g);
            const float4 va = vp[0];
            const float4 vb = vp[2];
            float acc[8];
#pragma unroll
            for (int rp = 0; rp < 4; ++rp) {
                const int woff = act ? ((c * 8 + 2 * rp + g) * WROW + o_m * 4)
                                     : (WZERO * WROW);
                const half8 a = *(const half8*)(wbase + woff);
                const f32x16 u = __builtin_amdgcn_mfma_f32_32x32x16_f16(a, xbr[rp], zero16, 0, 0, 0);
                const float p0 = u[0] * va.x + u[1] * va.y + u[2] * va.z + u[3] * va.w
                               + u[4] * vb.x + u[5] * vb.y + u[6] * vb.z + u[7] * vb.w;
                const float p1 = u[8] * va.x + u[9] * va.y + u[10] * va.z + u[11] * va.w
                               + u[12] * vb.x + u[13] * vb.y + u[14] * vb.z + u[15] * vb.w;
                const float send = g ? p0 : p1;
                const float recv = __shfl_xor(send, 32);
                const float pg = (g ? p1 : p0) + recv;
                const float w_own = __expf(pg) * dinv[rp];     // weight for r = 2rp+g
                const float w_oth = __shfl_xor(w_own, 32);     // partner's (r = 2rp+(1-g))
                const float c0 = g ? w_oth : w_own;            // r' = 0 rows (u[0..7])
                const float c1 = g ? w_own : w_oth;            // r' = 1 rows (u[8..15])
                if (rp == 0) {
#pragma unroll
                    for (int j = 0; j < 8; ++j) acc[j] = c0 * u[j] + c1 * u[j + 8];
                } else {
#pragma unroll
                    for (int j = 0; j < 8; ++j) acc[j] += c0 * u[j] + c1 * u[j + 8];
                }
            }
            RED_WRITE_AND_FLUSH(acc[0], acc[1], acc[2], acc[3],
                                acc[4], acc[5], acc[6], acc[7]);
        }
    } else {
        // ================= mode 0: uniform weights 0.1 =================
#pragma unroll 1
        for (int c = 0; c < C_; ++c) {
            f32x16 acc;
#pragma unroll
            for (int rp = 0; rp < 4; ++rp) {
                const int woff = act ? ((c * 8 + 2 * rp + g) * WROW + o_m * 4)
                                     : (WZERO * WROW);
                const half8 a = *(const half8*)(wbase + woff);
                // first rp consumes zero16 directly (no acc init copies)
                acc = __builtin_amdgcn_mfma_f32_32x32x16_f16(a, xbr[rp],
                                                             rp == 0 ? zero16 : acc, 0, 0, 0);
            }
            const float f0 = (acc[0] + acc[8])  * 0.1f, f1 = (acc[1] + acc[9])  * 0.1f;
            const float f2 = (acc[2] + acc[10]) * 0.1f, f3 = (acc[3] + acc[11]) * 0.1f;
            const float f4 = (acc[4] + acc[12]) * 0.1f, f5 = (acc[5] + acc[13]) * 0.1f;
            const float f6 = (acc[6] + acc[14]) * 0.1f, f7 = (acc[7] + acc[15]) * 0.1f;
            RED_WRITE_AND_FLUSH(f0, f1, f2, f3, f4, f5, f6, f7);
        }
    }
#undef RED_WRITE_AND_FLUSH
}

// ---------------------------------------------------------------------------
// finish_fused: single-level reduction of part (512 slots) + squash, replacing
// reduce1 + finish_pass (removes part2 traffic + one launch gap per iter).
// grid 320, block 512. Thread (q = tid>>5 in 0..15, pp = tid&31) sums slot
// range [q*32, q*32+32) at pair-index pi = blockIdx*32+pp (uint = 2 halfs;
// half-wave reads 128 B contiguous per slot). LDS tree 16 -> 1, then the
// first 32 lanes squash (8-lane shfl groups = 16 o's) and write.
// mode 0: vsum = v; 1: vsum += v; 2: out = v.
// ---------------------------------------------------------------------------
__global__ __launch_bounds__(512) void finish_fused(const __half* __restrict__ part,
                                                    float* __restrict__ vsum,   // [C][B][16]
                                                    float* __restrict__ out,    // [B][C][16]
                                                    int mode) {
    __shared__ float2 red[16][32];
    const int q  = threadIdx.x >> 5;           // slot-sixteenth 0..15
    const int pp = threadIdx.x & 31;
    const int pi = blockIdx.x * 32 + pp;       // t-pair index 0..10239

    const unsigned* pu = (const unsigned*)part + (size_t)q * 32 * (SBO / 2) + pi;
    float sx = 0.f, sy = 0.f;
#pragma unroll 8
    for (int s = 0; s < 32; ++s) {
        const unsigned uv = pu[(size_t)s * (SBO / 2)];
        const float2 f = __half22float2(*(const __half2*)&uv);
        sx += f.x; sy += f.y;
    }
    red[q][pp] = make_float2(sx, sy);
    __syncthreads();

    if (threadIdx.x < 32) {
        float2 s2 = red[0][pp];
#pragma unroll
        for (int j = 1; j < 16; ++j) { s2.x += red[j][pp].x; s2.y += red[j][pp].y; }

        float sq = s2.x * s2.x + s2.y * s2.y;
        sq += __shfl_xor(sq, 1);
        sq += __shfl_xor(sq, 2);
        sq += __shfl_xor(sq, 4);
        const float scale = sq / ((1.0f + sq) * sqrtf(sq + 1e-8f));
        const float v0 = scale * s2.x, v1 = scale * s2.y;
        const int t0 = 2 * pi;

        if (mode == 0) {
            *(float2*)(vsum + t0) = make_float2(v0, v1);
        } else if (mode == 1) {
            const float2 old = *(const float2*)(vsum + t0);
            *(float2*)(vsum + t0) = make_float2(old.x + v0, old.y + v1);
        } else {
            const int o = t0 & 15, b = (t0 >> 4) & 127, c = t0 >> 11;
            *(float2*)(out + ((size_t)b * C_ + c) * O_ + o) = make_float2(v0, v1);
        }
    }
}

extern "C" void kernel_launch(void* const* d_in, const int* in_sizes, int n_in,
                              void* d_out, int out_size, void* d_ws, size_t ws_size,
                              hipStream_t stream) {
    const float* x = (const float*)d_in[0];   // [B,R,8]
    const float* w = (const float*)d_in[1];   // [C,R,8,16]
    float* out = (float*)d_out;               // [B,C,16]

    __half* part = (__half*)d_ws;                          // 512*20480 fp16 = 21.0 MB
    float* vsum  = (float*)(part + (size_t)SLOTS * SBO);   // 20480 f ([C][B][16])

    const dim3 fgrid(R_ / 16);             // 512 blocks of 512 threads
    const dim3 ggrid(320);                 // finish_fused

    for (int it = 0; it < 3; ++it) {
        const int mode = (it > 0);
        const int fmode = (it == 2) ? 2 : it;   // finish: 0=set, 1=add, 2=out
        fused_iter<<<fgrid, 512, 0, stream>>>(x, w, vsum, part, mode);
        finish_fused<<<ggrid, 512, 0, stream>>>(part, vsum, out, fmode);
    }
}